// Round 9
// baseline (522.730 us; speedup 1.0000x reference)
//
#include <hip/hip_runtime.h>
#include <hip/hip_bf16.h>
#include <stdint.h>

#define BB  1024
#define SS  20
#define DD  128
#define G3  384      // 3*D
#define NII 100000
#define KXX 136      // D + R
#define RPB 2        // gru rows per block

typedef float  f32x4  __attribute__((ext_vector_type(4)));
typedef __bf16 bf16x8 __attribute__((ext_vector_type(8)));

__device__ __forceinline__ unsigned short f2bf(float x) {
  uint32_t u = __float_as_uint(x);
  uint32_t r = (u + 0x7fffu + ((u >> 16) & 1u)) >> 16;   // RNE
  return (unsigned short)r;
}

__device__ __forceinline__ float sigf(float x) { return 1.f / (1.f + expf(-x)); }

// ---------------- K_front: gx [0,2560) | zero_seg [2560,5120) | M [5120,5184) ----
__global__ __launch_bounds__(256) void k_front(const int* __restrict__ items,
                                               const float* __restrict__ rew,
                                               const float* __restrict__ table,
                                               const float* __restrict__ Wx,
                                               const float* __restrict__ bx,
                                               const float* __restrict__ Wu,
                                               const float* __restrict__ Wi,
                                               float* __restrict__ gx,
                                               float* __restrict__ sums,
                                               float* __restrict__ counts,
                                               float* __restrict__ M) {
  __shared__ float Wl[96][140];
  __shared__ float Al[32][128];
  __shared__ float rl[32];
  int bid = blockIdx.x;
  int t = threadIdx.x;
  if (bid < 2560) {
    // ---- gx: Mp=4 x Ng=3 tile ----
    int gt = bid & 3, pt = bid >> 2;
    int g0 = gt * 96, p0 = pt * 32;
    for (int i = t; i < 96 * 34; i += 256) {
      int r = i / 34, c = i % 34;
      f32x4 v = *(const f32x4*)(Wx + (size_t)(g0 + r) * KXX + c * 4);
      *(f32x4*)&Wl[r][c * 4] = v;
    }
    for (int i = t; i < 32 * 32; i += 256) {
      int r = i >> 5, c = i & 31;
      int it = items[p0 + r];
      *(f32x4*)&Al[r][c * 4] = *(const f32x4*)(table + (size_t)it * DD + c * 4);
    }
    if (t < 32) rl[t] = rew[p0 + t];
    __syncthreads();

    int tg = t & 31, pq = t >> 5;
    float acc[4][3] = {};
    for (int k4 = 0; k4 < 32; ++k4) {
      f32x4 a[4];
#pragma unroll
      for (int i = 0; i < 4; ++i) a[i] = *(f32x4*)&Al[pq + 8 * i][k4 * 4];
#pragma unroll
      for (int u = 0; u < 3; ++u) {
        f32x4 w = *(f32x4*)&Wl[tg + 32 * u][k4 * 4];
#pragma unroll
        for (int i = 0; i < 4; ++i)
          acc[i][u] += a[i].x * w.x + a[i].y * w.y + a[i].z * w.z + a[i].w * w.w;
      }
    }
#pragma unroll
    for (int u = 0; u < 3; ++u) {
      int gl = tg + 32 * u, g = g0 + gl;
      float wxr = 0.f;
#pragma unroll
      for (int q = 0; q < 8; ++q) wxr += Wl[gl][128 + q];
      float bxv = bx[g];
#pragma unroll
      for (int i = 0; i < 4; ++i) {
        int p = p0 + pq + 8 * i;
        gx[(size_t)p * G3 + g] = acc[i][u] + rl[pq + 8 * i] * wxr + bxv;
      }
    }
  } else if (bid < 5120) {
    // ---- zero touched sums/counts ----
    int id = (bid - 2560) * 256 + t;
    int p = id >> 5, c = id & 31;          // p < 20480 by construction
    int it = items[p];
    f32x4 z = {0.f, 0.f, 0.f, 0.f};
    *(f32x4*)(sums + (size_t)it * DD + c * 4) = z;
    if (c == 0) counts[it] = 0.f;
  } else {
    // ---- M = W_u @ W_i^T ----
    int idx = (bid - 5120) * 256 + t;
    int k1 = idx >> 7, k2 = idx & 127;
    float acc = 0.f;
    for (int e = 0; e < DD; ++e)
      acc = fmaf(Wu[k1 * DD + e], Wi[k2 * DD + e], acc);
    M[idx] = acc;
  }
}

// ---------------- K_gru: 384 threads, 2 Wh slices/thread (128 VGPR), 3 waves/SIMD,
//                  LDS hist + deferred tail atomics ----------------
__global__ __launch_bounds__(384, 3) void k_gru(const float* __restrict__ gx,
                                                const float* __restrict__ Wh,
                                                const float* __restrict__ bh,
                                                const int* __restrict__ items,
                                                float* __restrict__ sums,
                                                float* __restrict__ counts,
                                                float* __restrict__ hT) {
  __shared__ float hl[RPB][DD];
  __shared__ float ghl[RPB][G3];
  __shared__ float hist[RPB][SS][DD];    // 20 KB
  __shared__ int   itl[RPB][SS];
  int t = threadIdx.x;
  int gbase = t >> 1, half = t & 1;      // gbase 0..191

  f32x4 wreg[2][16];                     // g = tt*192 + gbase, cols half*64..+63
#pragma unroll
  for (int tt = 0; tt < 2; ++tt) {
    const float* src = Wh + (size_t)(tt * 192 + gbase) * DD + half * 64;
#pragma unroll
    for (int j4 = 0; j4 < 16; ++j4)
      wreg[tt][j4] = *(const f32x4*)(src + j4 * 4);
  }

  int b0 = blockIdx.x * RPB;
  if (t < RPB * SS) itl[t / SS][t % SS] = items[(b0 + t / SS) * SS + t % SS];

  int u2 = t >> 7, w2 = t & 127;         // phase-2 identity (t < 256)
  float bh3[3] = {0.f, 0.f, 0.f};
  if (t < 256) {
#pragma unroll
    for (int q = 0; q < 3; ++q) bh3[q] = bh[q * 128 + w2];
    hl[u2][w2] = 0.f;
  }
  const float* gxb = gx + (size_t)(b0 + (u2 < RPB ? u2 : 0)) * SS * G3;
  float hcur = 0.f;
  __syncthreads();

  for (int s = 0; s < SS; ++s) {
    float g3v[3] = {0.f, 0.f, 0.f};
    if (t < 256) {
#pragma unroll
      for (int q = 0; q < 3; ++q) g3v[q] = gxb[s * G3 + q * 128 + w2];
    }
    // phase 1: every thread, 2 slices x RPB rows
#pragma unroll
    for (int r = 0; r < RPB; ++r) {
      float a0 = 0.f, a1 = 0.f;
#pragma unroll
      for (int j4 = 0; j4 < 16; ++j4) {
        f32x4 hv = *(f32x4*)&hl[r][half * 64 + j4 * 4];
        a0 += wreg[0][j4].x * hv.x + wreg[0][j4].y * hv.y
            + wreg[0][j4].z * hv.z + wreg[0][j4].w * hv.w;
        a1 += wreg[1][j4].x * hv.x + wreg[1][j4].y * hv.y
            + wreg[1][j4].z * hv.z + wreg[1][j4].w * hv.w;
      }
      a0 += __shfl_xor(a0, 1);
      a1 += __shfl_xor(a1, 1);
      if (!half) {
        ghl[r][gbase]       = a0;    // g in [0,192)
        ghl[r][192 + gbase] = a1;    // g in [192,384)
      }
    }
    __syncthreads();
    // phase 2: threads 0-255 update h
    if (t < 256) {
      float rr = sigf(g3v[0] + ghl[u2][w2]       + bh3[0]);
      float zz = sigf(g3v[1] + ghl[u2][128 + w2] + bh3[1]);
      float nn = tanhf(g3v[2] + rr * (ghl[u2][256 + w2] + bh3[2]));
      hcur = (1.f - zz) * nn + zz * hcur;
      hl[u2][w2] = hcur;
      hist[u2][s][w2] = hcur;
    }
    __syncthreads();
  }
  if (t < 256) hT[(b0 + u2) * DD + w2] = hcur;
  // deferred tail atomics, spread over all 384 threads, single drain at exit
  for (int idx = t; idx < RPB * SS * DD; idx += 384) {
    int r = idx / (SS * DD), rem = idx % (SS * DD);
    int s = rem / DD, d = rem % DD;
    atomicAdd(sums + (size_t)itl[r][s] * DD + d, hist[r][s][d]);
  }
  if (t < RPB * SS) atomicAdd(counts + itl[t / SS][t % SS], 1.f);
}

// ---------------- K_back: items [0,12500) | uprime [12500,12564) ----------------
__global__ __launch_bounds__(256) void k_back(const float* __restrict__ table,
                                              const float* __restrict__ mem,
                                              const float* __restrict__ sums,
                                              const float* __restrict__ counts,
                                              unsigned short* __restrict__ Ibf,
                                              const int* __restrict__ ids,
                                              const float* __restrict__ hT,
                                              const float* __restrict__ M,
                                              unsigned short* __restrict__ Ubf) {
  __shared__ int   idsl[BB];
  __shared__ int   repl[16][16];
  __shared__ float hTl[16][DD];
  int bid = blockIdx.x;
  int t = threadIdx.x;
  if (bid < 12500) {
    // ---- items_input -> bf16 ----
    size_t tid = (size_t)bid * 256 + t;
    size_t i = tid >> 5; int c = (int)(tid & 31);
    if (i >= NII) return;
    float cnt = counts[i];
    size_t base = i * DD + c * 4;
    f32x4 m  = *(const f32x4*)(mem + base);
    f32x4 tb = *(const f32x4*)(table + base);
    float vx, vy, vz, vw;
    if (cnt > 0.f) {
      f32x4 sm = *(const f32x4*)(sums + base);
      vx = 0.5f * (m.x + sm.x / cnt) + tb.x;
      vy = 0.5f * (m.y + sm.y / cnt) + tb.y;
      vz = 0.5f * (m.z + sm.z / cnt) + tb.z;
      vw = 0.5f * (m.w + sm.w / cnt) + tb.w;
    } else {
      vx = m.x + tb.x; vy = m.y + tb.y; vz = m.z + tb.z; vw = m.w + tb.w;
    }
    unsigned long long pack = (unsigned long long)f2bf(vx)
                            | ((unsigned long long)f2bf(vy) << 16)
                            | ((unsigned long long)f2bf(vz) << 32)
                            | ((unsigned long long)f2bf(vw) << 48);
    *(unsigned long long*)(Ibf + base) = pack;
  } else {
    // ---- rep (last-write-wins) + U' = hT[rep] @ M -> bf16 ----
    int ub = bid - 12500;
    for (int i = t; i < BB; i += 256) idsl[i] = ids[i];
    __syncthreads();
    int b0 = ub * 16;
    int p = t >> 4, c = t & 15;
    int myid = idsl[b0 + p];
    int best = -1;
    for (int j = c * 64; j < c * 64 + 64; ++j)
      if (idsl[j] == myid) best = j;
    repl[p][c] = best;
    __syncthreads();
    if (c == 0) {
      int rr = -1;
#pragma unroll
      for (int q = 0; q < 16; ++q) rr = max(rr, repl[p][q]);
      repl[p][0] = rr;
    }
    __syncthreads();
    for (int i = t; i < 16 * 32; i += 256) {
      int rr = i >> 5, c4 = i & 31;
      int src = repl[rr][0];
      *(f32x4*)&hTl[rr][c4 * 4] = *(const f32x4*)(hT + (size_t)src * DD + c4 * 4);
    }
    __syncthreads();
    float acc[8] = {0.f, 0.f, 0.f, 0.f, 0.f, 0.f, 0.f, 0.f};
    for (int k1 = 0; k1 < DD; ++k1) {
      float hv = hTl[p][k1];
#pragma unroll
      for (int u = 0; u < 8; ++u)
        acc[u] = fmaf(hv, M[k1 * DD + c + 16 * u], acc[u]);
    }
#pragma unroll
    for (int u = 0; u < 8; ++u)
      Ubf[(size_t)(b0 + p) * DD + c + 16 * u] = f2bf(acc[u]);
  }
}

// ---------------- K_gemm: swapped-operand MFMA, j-strip persistent-A,
//                  bijective XCD swizzle for L2 write-merging ----------------
__device__ __forceinline__ bf16x8 bzero8() {
  bf16x8 z;
#pragma unroll
  for (int e = 0; e < 8; ++e) z[e] = (__bf16)0.f;
  return z;
}

__global__ __launch_bounds__(256) void k_gemm(const unsigned short* __restrict__ Ubf,
                                              const unsigned short* __restrict__ Ibf,
                                              float* __restrict__ out) {
  // bijective XCD swizzle: consecutive j-strips -> same XCD (merge row segments in L2)
  int nb = gridDim.x;                 // 1563
  int q = nb >> 3, rr = nb & 7;
  int xcd = blockIdx.x & 7, ii = blockIdx.x >> 3;
  int strip = (xcd < rr) ? (xcd * (q + 1) + ii)
                         : (rr * (q + 1) + (xcd - rr) * q + ii);
  int j0 = strip * 64;

  int t = threadIdx.x;
  int wv = t >> 6, l = t & 63;
  int wr = wv >> 1, wc = wv & 1;
  int jw = j0 + wc * 32;
  int lr = l & 15, lk = l >> 4;

  bf16x8 afrag[4][2];
  int ja0 = jw + lr, ja1 = jw + 16 + lr;
#pragma unroll
  for (int kk = 0; kk < 4; ++kk) {
    int k0 = kk * 32 + lk * 8;
    afrag[kk][0] = (ja0 < NII) ? *(const bf16x8*)(Ibf + (size_t)ja0 * DD + k0) : bzero8();
    afrag[kk][1] = (ja1 < NII) ? *(const bf16x8*)(Ibf + (size_t)ja1 * DD + k0) : bzero8();
  }
  int jb0 = jw + lk * 4;
  bool v0 = (jb0 < NII), v1 = (jb0 + 16 < NII);

  for (int bc = 0; bc < 16; ++bc) {
    int bw = bc * 64 + wr * 32;
    f32x4 acc[2][2];
#pragma unroll
    for (int ji = 0; ji < 2; ++ji)
#pragma unroll
      for (int bi = 0; bi < 2; ++bi) { f32x4 z = {0.f,0.f,0.f,0.f}; acc[ji][bi] = z; }

#pragma unroll
    for (int kk = 0; kk < 4; ++kk) {
      int k0 = kk * 32 + lk * 8;
      bf16x8 b0 = *(const bf16x8*)(Ubf + (size_t)(bw + lr) * DD + k0);
      bf16x8 b1 = *(const bf16x8*)(Ubf + (size_t)(bw + 16 + lr) * DD + k0);
      acc[0][0] = __builtin_amdgcn_mfma_f32_16x16x32_bf16(afrag[kk][0], b0, acc[0][0], 0, 0, 0);
      acc[0][1] = __builtin_amdgcn_mfma_f32_16x16x32_bf16(afrag[kk][0], b1, acc[0][1], 0, 0, 0);
      acc[1][0] = __builtin_amdgcn_mfma_f32_16x16x32_bf16(afrag[kk][1], b0, acc[1][0], 0, 0, 0);
      acc[1][1] = __builtin_amdgcn_mfma_f32_16x16x32_bf16(afrag[kk][1], b1, acc[1][1], 0, 0, 0);
    }
#pragma unroll
    for (int ji = 0; ji < 2; ++ji) {
      if (ji ? v1 : v0) {
        int jb = jw + ji * 16 + lk * 4;
#pragma unroll
        for (int bi = 0; bi < 2; ++bi) {
          int bb = bw + bi * 16 + lr;
          *(f32x4*)(out + (size_t)bb * NII + jb) = acc[ji][bi];
        }
      }
    }
  }
}

extern "C" void kernel_launch(void* const* d_in, const int* in_sizes, int n_in,
                              void* d_out, int out_size, void* d_ws, size_t ws_size,
                              hipStream_t stream) {
  const int*   users_ids   = (const int*)  d_in[0];
  const int*   users_items = (const int*)  d_in[1];
  const float* users_rew   = (const float*)d_in[2];
  const float* items_table = (const float*)d_in[4];
  const float* items_mem   = (const float*)d_in[6];
  const float* Wx  = (const float*)d_in[7];
  const float* Wh  = (const float*)d_in[8];
  const float* bx  = (const float*)d_in[9];
  const float* bh  = (const float*)d_in[10];
  const float* W_u = (const float*)d_in[11];
  const float* W_i = (const float*)d_in[12];
  float* out = (float*)d_out;
  (void)in_sizes; (void)n_in; (void)out_size; (void)ws_size;

  char* ws = (char*)d_ws;
  size_t off = 0;
  auto alloc = [&](size_t bytes) {
    void* p = ws + off;
    off = (off + bytes + 255) & ~(size_t)255;
    return p;
  };
  float* sums   = (float*)alloc(sizeof(float) * (size_t)NII * DD);
  float* counts = (float*)alloc(sizeof(float) * NII);
  float* gx     = (float*)alloc(sizeof(float) * (size_t)BB * SS * G3);
  float* M      = (float*)alloc(sizeof(float) * DD * DD);
  float* hT     = (float*)alloc(sizeof(float) * BB * DD);
  unsigned short* Ubf = (unsigned short*)alloc(sizeof(unsigned short) * BB * DD);
  unsigned short* Ibf = (unsigned short*)alloc(sizeof(unsigned short) * (size_t)NII * DD);

  hipLaunchKernelGGL(k_front, dim3(5184), dim3(256), 0, stream,
                     users_items, users_rew, items_table, Wx, bx, W_u, W_i,
                     gx, sums, counts, M);
  hipLaunchKernelGGL(k_gru, dim3(BB / RPB), dim3(384), 0, stream,
                     gx, Wh, bh, users_items, sums, counts, hT);
  hipLaunchKernelGGL(k_back, dim3(12564), dim3(256), 0, stream,
                     items_table, items_mem, sums, counts, Ibf,
                     users_ids, hT, M, Ubf);
  // ABLATION PROBE retained: k_gemm twice (idempotent). Next round removes the
  // duplicate; r9 - r10 = G + gap exactly.
  hipLaunchKernelGGL(k_gemm, dim3((NII + 63) / 64), dim3(256), 0, stream,
                     Ubf, Ibf, out);
  hipLaunchKernelGGL(k_gemm, dim3((NII + 63) / 64), dim3(256), 0, stream,
                     Ubf, Ibf, out);
}

// Round 10
// 281.574 us; speedup vs baseline: 1.8565x; 1.8565x over previous
//
#include <hip/hip_runtime.h>
#include <hip/hip_bf16.h>
#include <stdint.h>

#define BB  1024
#define SS  20
#define DD  128
#define G3  384      // 3*D
#define NII 100000
#define KXX 136      // D + R
#define RPB 2        // gru rows per block
#define JPB 256      // gemm j-columns per block

typedef float  f32x4  __attribute__((ext_vector_type(4)));
typedef __bf16 bf16x8 __attribute__((ext_vector_type(8)));

__device__ __forceinline__ unsigned short f2bf(float x) {
  uint32_t u = __float_as_uint(x);
  uint32_t r = (u + 0x7fffu + ((u >> 16) & 1u)) >> 16;   // RNE
  return (unsigned short)r;
}

__device__ __forceinline__ float sigf(float x) { return 1.f / (1.f + expf(-x)); }

// ---------------- K1: zero sums/counts for touched items ----------------
__global__ __launch_bounds__(256) void k_zero_seg(const int* __restrict__ items,
                                                  float* __restrict__ sums,
                                                  float* __restrict__ counts) {
  int tid = blockIdx.x * 256 + threadIdx.x;
  int p = tid >> 5, c = tid & 31;
  if (p >= BB * SS) return;
  int it = items[p];
  f32x4 z = {0.f, 0.f, 0.f, 0.f};
  *(f32x4*)(sums + (size_t)it * DD + c * 4) = z;
  if (c == 0) counts[it] = 0.f;
}

// ---------------- K3: M = W_u @ W_i^T  (128x128) ----------------
__global__ __launch_bounds__(256) void k_M(const float* __restrict__ Wu,
                                           const float* __restrict__ Wi,
                                           float* __restrict__ M) {
  int idx = blockIdx.x * 256 + threadIdx.x;  // 16384 total
  int k1 = idx >> 7, k2 = idx & 127;
  float acc = 0.f;
  for (int e = 0; e < DD; ++e)
    acc = fmaf(Wu[k1 * DD + e], Wi[k2 * DD + e], acc);
  M[idx] = acc;
}

// ---------------- K4: gx[p][g] = x[p] . Wx[g] + bx[g]  (Mp=4 x Ng=3 tile) ----
__global__ __launch_bounds__(256) void k_gx(const int* __restrict__ items,
                                            const float* __restrict__ rew,
                                            const float* __restrict__ table,
                                            const float* __restrict__ Wx,
                                            const float* __restrict__ bx,
                                            float* __restrict__ gx) {
  __shared__ float Wl[96][140];
  __shared__ float Al[32][128];
  __shared__ float rl[32];
  int gt = blockIdx.x & 3, pt = blockIdx.x >> 2;
  int g0 = gt * 96, p0 = pt * 32;
  int t = threadIdx.x;
  for (int i = t; i < 96 * 34; i += 256) {           // 136 cols = 34 float4
    int r = i / 34, c = i % 34;
    f32x4 v = *(const f32x4*)(Wx + (size_t)(g0 + r) * KXX + c * 4);
    *(f32x4*)&Wl[r][c * 4] = v;
  }
  for (int i = t; i < 32 * 32; i += 256) {
    int r = i >> 5, c = i & 31;
    int it = items[p0 + r];
    *(f32x4*)&Al[r][c * 4] = *(const f32x4*)(table + (size_t)it * DD + c * 4);
  }
  if (t < 32) rl[t] = rew[p0 + t];
  __syncthreads();

  int tg = t & 31, pq = t >> 5;        // g-group 0..31, p-group 0..7
  float acc[4][3] = {};
  for (int k4 = 0; k4 < 32; ++k4) {
    f32x4 a[4];
#pragma unroll
    for (int i = 0; i < 4; ++i) a[i] = *(f32x4*)&Al[pq + 8 * i][k4 * 4];
#pragma unroll
    for (int u = 0; u < 3; ++u) {
      f32x4 w = *(f32x4*)&Wl[tg + 32 * u][k4 * 4];
#pragma unroll
      for (int i = 0; i < 4; ++i)
        acc[i][u] += a[i].x * w.x + a[i].y * w.y + a[i].z * w.z + a[i].w * w.w;
    }
  }
#pragma unroll
  for (int u = 0; u < 3; ++u) {
    int gl = tg + 32 * u, g = g0 + gl;
    float wxr = 0.f;
#pragma unroll
    for (int q = 0; q < 8; ++q) wxr += Wl[gl][128 + q];
    float bxv = bx[g];
#pragma unroll
    for (int i = 0; i < 4; ++i) {
      int p = p0 + pq + 8 * i;
      gx[(size_t)p * G3 + g] = acc[i][u] + rl[pq + 8 * i] * wxr + bxv;
    }
  }
}

// ---------------- K5: GRU, 2 rows/block, register Wh, in-loop atomics ----------------
// (byte-identical to round 8)
__global__ __launch_bounds__(256, 2) void k_gru(const float* __restrict__ gx,
                                                const float* __restrict__ Wh,
                                                const float* __restrict__ bh,
                                                const int* __restrict__ items,
                                                float* __restrict__ sums,
                                                float* __restrict__ counts,
                                                float* __restrict__ hT) {
  __shared__ float hl[RPB][DD];        // h per row
  __shared__ float ghl[RPB][G3];       // Wh @ h per row
  int t = threadIdx.x;
  int gbase = t >> 1, half = t & 1;    // phase-1 identity: g in gate-block, k-half

  f32x4 wreg[3][16];
#pragma unroll
  for (int tt = 0; tt < 3; ++tt) {
    const float* src = Wh + (size_t)(tt * 128 + gbase) * DD + half * 64;
#pragma unroll
    for (int j4 = 0; j4 < 16; ++j4)
      wreg[tt][j4] = *(const f32x4*)(src + j4 * 4);
  }

  int u2 = t >> 7, w2 = t & 127;       // phase-2 identity: row, d-element
  float bh3[3];
#pragma unroll
  for (int q = 0; q < 3; ++q) bh3[q] = bh[q * 128 + w2];

  int b0 = blockIdx.x * RPB;
  const float* gxb = gx + (size_t)(b0 + u2) * SS * G3;
  const int*   itb = items + (b0 + u2) * SS;
  hl[u2][w2] = 0.f;
  float hcur = 0.f;
  __syncthreads();

  for (int s = 0; s < SS; ++s) {
    float g3[3];
#pragma unroll
    for (int q = 0; q < 3; ++q) g3[q] = gxb[s * G3 + q * 128 + w2];
    int it = itb[s];

#pragma unroll
    for (int r = 0; r < RPB; ++r) {
      float a0 = 0.f, a1 = 0.f, a2 = 0.f;
#pragma unroll
      for (int j4 = 0; j4 < 16; ++j4) {
        f32x4 hv = *(f32x4*)&hl[r][half * 64 + j4 * 4];
        a0 += wreg[0][j4].x * hv.x + wreg[0][j4].y * hv.y
            + wreg[0][j4].z * hv.z + wreg[0][j4].w * hv.w;
        a1 += wreg[1][j4].x * hv.x + wreg[1][j4].y * hv.y
            + wreg[1][j4].z * hv.z + wreg[1][j4].w * hv.w;
        a2 += wreg[2][j4].x * hv.x + wreg[2][j4].y * hv.y
            + wreg[2][j4].z * hv.z + wreg[2][j4].w * hv.w;
      }
      a0 += __shfl_xor(a0, 1);
      a1 += __shfl_xor(a1, 1);
      a2 += __shfl_xor(a2, 1);
      if (!half) {
        ghl[r][gbase]       = a0;
        ghl[r][128 + gbase] = a1;
        ghl[r][256 + gbase] = a2;
      }
    }
    __syncthreads();
    float rr = sigf(g3[0] + ghl[u2][w2]       + bh3[0]);
    float zz = sigf(g3[1] + ghl[u2][128 + w2] + bh3[1]);
    float nn = tanhf(g3[2] + rr * (ghl[u2][256 + w2] + bh3[2]));
    hcur = (1.f - zz) * nn + zz * hcur;
    hl[u2][w2] = hcur;
    atomicAdd(sums + (size_t)it * DD + w2, hcur);
    if (w2 == 0) atomicAdd(counts + it, 1.f);
    __syncthreads();
  }
  hT[(b0 + u2) * DD + w2] = hcur;
}

// ---------------- K6: items_input (bf16) ----------------
__global__ __launch_bounds__(256) void k_items(const float* __restrict__ table,
                                               const float* __restrict__ mem,
                                               const float* __restrict__ sums,
                                               const float* __restrict__ counts,
                                               unsigned short* __restrict__ Ibf) {
  size_t tid = (size_t)blockIdx.x * 256 + threadIdx.x;
  size_t i = tid >> 5; int c = (int)(tid & 31);
  if (i >= NII) return;
  float cnt = counts[i];
  size_t base = i * DD + c * 4;
  f32x4 m  = *(const f32x4*)(mem + base);
  f32x4 tb = *(const f32x4*)(table + base);
  float vx, vy, vz, vw;
  if (cnt > 0.f) {
    f32x4 sm = *(const f32x4*)(sums + base);
    vx = 0.5f * (m.x + sm.x / cnt) + tb.x;
    vy = 0.5f * (m.y + sm.y / cnt) + tb.y;
    vz = 0.5f * (m.z + sm.z / cnt) + tb.z;
    vw = 0.5f * (m.w + sm.w / cnt) + tb.w;
  } else {
    vx = m.x + tb.x; vy = m.y + tb.y; vz = m.z + tb.z; vw = m.w + tb.w;
  }
  unsigned long long pack = (unsigned long long)f2bf(vx)
                          | ((unsigned long long)f2bf(vy) << 16)
                          | ((unsigned long long)f2bf(vz) << 32)
                          | ((unsigned long long)f2bf(vw) << 48);
  *(unsigned long long*)(Ibf + base) = pack;
}

// ---------------- K7: rep (last-write-wins) + U' = hT[rep] @ M  -> bf16 ----------------
__global__ __launch_bounds__(256) void k_uprime(const int* __restrict__ ids,
                                                const float* __restrict__ hT,
                                                const float* __restrict__ M,
                                                unsigned short* __restrict__ Ubf) {
  __shared__ int   idsl[BB];
  __shared__ int   repl[16][16];
  __shared__ float hTl[16][DD];
  int t = threadIdx.x;
  for (int i = t; i < BB; i += 256) idsl[i] = ids[i];
  __syncthreads();
  int b0 = blockIdx.x * 16;
  int p = t >> 4, c = t & 15;
  int myid = idsl[b0 + p];
  int best = -1;
  for (int j = c * 64; j < c * 64 + 64; ++j)
    if (idsl[j] == myid) best = j;
  repl[p][c] = best;
  __syncthreads();
  if (c == 0) {
    int rr = -1;
#pragma unroll
    for (int q = 0; q < 16; ++q) rr = max(rr, repl[p][q]);
    repl[p][0] = rr;
  }
  __syncthreads();
  for (int i = t; i < 16 * 32; i += 256) {
    int rr = i >> 5, c4 = i & 31;
    int src = repl[rr][0];
    *(f32x4*)&hTl[rr][c4 * 4] = *(const f32x4*)(hT + (size_t)src * DD + c4 * 4);
  }
  __syncthreads();
  float acc[8] = {0.f, 0.f, 0.f, 0.f, 0.f, 0.f, 0.f, 0.f};
  for (int k1 = 0; k1 < DD; ++k1) {
    float hv = hTl[p][k1];
#pragma unroll
    for (int u = 0; u < 8; ++u)
      acc[u] = fmaf(hv, M[k1 * DD + c + 16 * u], acc[u]);
  }
#pragma unroll
  for (int u = 0; u < 8; ++u)
    Ubf[(size_t)(b0 + p) * DD + c + 16 * u] = f2bf(acc[u]);
}

// ---------------- K8: out = U' @ I^T  (swapped MFMA, 256-wide j tile,
//   LDS-staged epilogue: one wave stores one ROW = 1024 B contiguous per
//   store instruction -> fillBuffer-shaped HBM write bursts) ----------------
__device__ __forceinline__ bf16x8 bzero8() {
  bf16x8 z;
#pragma unroll
  for (int e = 0; e < 8; ++e) z[e] = (__bf16)0.f;
  return z;
}

__global__ __launch_bounds__(256, 2) void k_gemm(const unsigned short* __restrict__ Ubf,
                                                 const unsigned short* __restrict__ Ibf,
                                                 float* __restrict__ out) {
  __shared__ float ldsT[64][JPB + 4];   // pad 4: +1 bank rotation per b-row
  int j0 = blockIdx.x * JPB;
  int t = threadIdx.x;
  int wv = t >> 6, l = t & 63;
  int jw = j0 + wv * 64;                // wave owns a 64-wide j window
  int lr = l & 15, lk = l >> 4;

  // persistent A (Ibf) fragments: 4 j-16-tiles x 4 k-steps = 64 VGPR
  bf16x8 afrag[4][4];
#pragma unroll
  for (int ji = 0; ji < 4; ++ji) {
    int ja = jw + ji * 16 + lr;
#pragma unroll
    for (int kk = 0; kk < 4; ++kk) {
      int k0 = kk * 32 + lk * 8;
      afrag[ji][kk] = (ja < NII) ? *(const bf16x8*)(Ibf + (size_t)ja * DD + k0) : bzero8();
    }
  }
  int jcl = l * 4;                       // store-phase column (floats)
  bool svalid = (j0 + jcl + 4 <= NII);   // NII % 4 == 0

  for (int bc = 0; bc < 16; ++bc) {
    int bw = bc * 64;
    f32x4 acc[4][4];                     // [ji][bi]
#pragma unroll
    for (int ji = 0; ji < 4; ++ji)
#pragma unroll
      for (int bi = 0; bi < 4; ++bi) { f32x4 z = {0.f,0.f,0.f,0.f}; acc[ji][bi] = z; }

#pragma unroll
    for (int kk = 0; kk < 4; ++kk) {
      int k0 = kk * 32 + lk * 8;
#pragma unroll
      for (int bi = 0; bi < 4; ++bi) {
        bf16x8 bfr = *(const bf16x8*)(Ubf + (size_t)(bw + bi * 16 + lr) * DD + k0);
#pragma unroll
        for (int ji = 0; ji < 4; ++ji)
          acc[ji][bi] = __builtin_amdgcn_mfma_f32_16x16x32_bf16(afrag[ji][kk], bfr,
                                                                acc[ji][bi], 0, 0, 0);
      }
    }
    // D layout (swapped): col=lane&15 -> b_local = bi*16 + lr
    //                     row=(lane>>4)*4+q -> j_local = wv*64 + ji*16 + lk*4 + q
    __syncthreads();                     // previous store-phase reads complete
#pragma unroll
    for (int ji = 0; ji < 4; ++ji) {
      int jl = wv * 64 + ji * 16 + lk * 4;
#pragma unroll
      for (int bi = 0; bi < 4; ++bi)
        *(f32x4*)&ldsT[bi * 16 + lr][jl] = acc[ji][bi];
    }
    __syncthreads();
    if (svalid) {
#pragma unroll
      for (int rr = 0; rr < 16; ++rr) {
        int row = rr * 4 + wv;           // one wave -> one row -> 1024 B burst
        f32x4 v = *(f32x4*)&ldsT[row][jcl];
        *(f32x4*)(out + (size_t)(bw + row) * NII + j0 + jcl) = v;
      }
    }
  }
}

extern "C" void kernel_launch(void* const* d_in, const int* in_sizes, int n_in,
                              void* d_out, int out_size, void* d_ws, size_t ws_size,
                              hipStream_t stream) {
  const int*   users_ids   = (const int*)  d_in[0];
  const int*   users_items = (const int*)  d_in[1];
  const float* users_rew   = (const float*)d_in[2];
  const float* items_table = (const float*)d_in[4];
  const float* items_mem   = (const float*)d_in[6];
  const float* Wx  = (const float*)d_in[7];
  const float* Wh  = (const float*)d_in[8];
  const float* bx  = (const float*)d_in[9];
  const float* bh  = (const float*)d_in[10];
  const float* W_u = (const float*)d_in[11];
  const float* W_i = (const float*)d_in[12];
  float* out = (float*)d_out;
  (void)in_sizes; (void)n_in; (void)out_size; (void)ws_size;

  char* ws = (char*)d_ws;
  size_t off = 0;
  auto alloc = [&](size_t bytes) {
    void* p = ws + off;
    off = (off + bytes + 255) & ~(size_t)255;
    return p;
  };
  float* sums   = (float*)alloc(sizeof(float) * (size_t)NII * DD);
  float* counts = (float*)alloc(sizeof(float) * NII);
  float* gx     = (float*)alloc(sizeof(float) * (size_t)BB * SS * G3);
  float* M      = (float*)alloc(sizeof(float) * DD * DD);
  float* hT     = (float*)alloc(sizeof(float) * BB * DD);
  unsigned short* Ubf = (unsigned short*)alloc(sizeof(unsigned short) * BB * DD);
  unsigned short* Ibf = (unsigned short*)alloc(sizeof(unsigned short) * (size_t)NII * DD);

  hipLaunchKernelGGL(k_zero_seg, dim3((BB * SS * 32) / 256), dim3(256), 0, stream,
                     users_items, sums, counts);
  hipLaunchKernelGGL(k_M, dim3(64), dim3(256), 0, stream, W_u, W_i, M);
  hipLaunchKernelGGL(k_gx, dim3((BB * SS / 32) * 4), dim3(256), 0, stream,
                     users_items, users_rew, items_table, Wx, bx, gx);
  hipLaunchKernelGGL(k_gru, dim3(BB / RPB), dim3(256), 0, stream,
                     gx, Wh, bh, users_items, sums, counts, hT);
  hipLaunchKernelGGL(k_items, dim3((NII * 32 + 255) / 256), dim3(256), 0, stream,
                     items_table, items_mem, sums, counts, Ibf);
  hipLaunchKernelGGL(k_uprime, dim3(BB / 16), dim3(256), 0, stream,
                     users_ids, hT, M, Ubf);
  hipLaunchKernelGGL(k_gemm, dim3((NII + JPB - 1) / JPB), dim3(256), 0, stream,
                     Ubf, Ibf, out);
}